// Round 3
// baseline (236.613 us; speedup 1.0000x reference)
//
#include <hip/hip_runtime.h>

#define HW_S   65536      // 256*256 small image pixels
#define NFEAT  10
#define DIM    33
#define DIM3   35937      // 33^3
#define LUT_ELEMS (3*DIM3)
#define IMG_HW 8294400    // 2160*3840
#define IMG_ELEMS (3*IMG_HW)
#define NGROUPS (IMG_HW/4)

typedef float f32x4 __attribute__((ext_vector_type(4)));

// ws layout (32-bit slots): [0]=amax bits, [1]=counter, [16..2576)=partials,
// [4096..5086)=K

// ---------------- Stage 1: gather+pool, last block computes K ---------------
__global__ __launch_bounds__(256) void feat_and_K(
    const int* __restrict__ msb, const int* __restrict__ lsb,
    const float* __restrict__ fm, const float* __restrict__ fl,
    const float* __restrict__ lut_cat, const float* __restrict__ s_layers,
    const float* __restrict__ luts,
    float* __restrict__ partial, unsigned int* __restrict__ counter,
    float* __restrict__ Kout)
{
    int tid = threadIdx.x;
    int p = blockIdx.x * 256 + tid;
    int im = msb[p] * 4096 + msb[HW_S + p] * 256 + msb[2 * HW_S + p] * 16;
    int il = lsb[p] * 4096 + lsb[HW_S + p] * 256 + lsb[2 * HW_S + p] * 16;
    const float2* rm = (const float2*)(fm + im * NFEAT);  // 40B rows: 8B aligned
    const float2* rl = (const float2*)(fl + il * NFEAT);
    float acc[NFEAT];
#pragma unroll
    for (int h = 0; h < 5; ++h) {
        float2 a = rm[h], b = rl[h];
        acc[2 * h]     = a.x + b.x;
        acc[2 * h + 1] = a.y + b.y;
    }
#pragma unroll
    for (int f = 0; f < NFEAT; ++f) {
        float v = acc[f];
#pragma unroll
        for (int off = 32; off >= 1; off >>= 1) v += __shfl_down(v, off, 64);
        acc[f] = v;
    }
    __shared__ float s4[4][NFEAT];
    int lane = tid & 63, wave = tid >> 6;
    if (lane == 0) {
#pragma unroll
        for (int f = 0; f < NFEAT; ++f) s4[wave][f] = acc[f];
    }
    __syncthreads();
    if (tid < NFEAT)
        partial[blockIdx.x * NFEAT + tid] =
            s4[0][tid] + s4[1][tid] + s4[2][tid] + s4[3][tid];

    // ---- last-block finalization (decoupled, device-scope fenced) ----
    __shared__ int lastflag;
    __syncthreads();   // drains the partial[] stores (s_waitcnt vmcnt(0) before barrier)
    if (tid == 0) {
        __threadfence();
        lastflag = (atomicAdd(counter, 1u) == 255u) ? 1 : 0;
    }
    __syncthreads();
    if (!lastflag) return;
    __threadfence();   // acquire: invalidate stale lines before reading partials

    __shared__ float chunk_s[80];
    __shared__ float pooled_s[NFEAT], w_s[NFEAT], R_s[150];
    if (tid < 80) {   // fixed-order tree: 8 chunks x 32 blocks, per feature
        int f = tid % 10, ch = tid / 10;
        float s = 0.f;
        for (int b = ch * 32; b < ch * 32 + 32; ++b) s += partial[b * NFEAT + f];
        chunk_s[tid] = s;
    }
    __syncthreads();
    if (tid < NFEAT) {
        float v = 0.f;
#pragma unroll
        for (int ch = 0; ch < 8; ++ch) v += chunk_s[ch * 10 + tid];
        v *= (1.0f / 65536.0f);
        v = rintf(v * 2.0f) * 0.5f;
        v = fminf(fmaxf(v, -16.0f), 15.5f);
        pooled_s[tid] = v;
    }
    __syncthreads();
    if (tid < NFEAT) {
        float wsum = 0.f;
        for (int i = 0; i < 5; ++i) {
            int m0 = (int)(pooled_s[2 * i] * 2.0f) + 32;
            int m1 = (int)(pooled_s[2 * i + 1] * 2.0f) + 32;
            wsum += (lut_cat[(i * 4096 + m0 * 64 + m1) * NFEAT + tid] - 32.0f) * 0.25f;
        }
        w_s[tid] = wsum;
    }
    __syncthreads();
    if (tid < 150) {  // R[s][c][w] = sum_n weights[n] * luts[s*30+n*3+c, w]
        int w = tid % 10, sc = tid / 10, c = sc % 3, s = sc / 3;
        float r = 0.f;
        for (int n = 0; n < NFEAT; ++n)
            r += w_s[n] * luts[(s * 30 + n * 3 + c) * NFEAT + w];
        R_s[tid] = r;
    }
    __syncthreads();
    for (int t = tid; t < 3 * DIM * NFEAT; t += 256) {  // K[c][a][w]
        int w = t % 10, a = (t / 10) % DIM, c = t / (10 * DIM);
        float k = 0.f;
#pragma unroll
        for (int s = 0; s < 5; ++s)
            k += s_layers[a * 5 + s] * R_s[(s * 3 + c) * 10 + w];
        Kout[t] = k;
    }
}

// ---------------- Stage 2: materialize d3lut (f32) + global absmax ----------
__global__ __launch_bounds__(256) void compute_lut(
    const float* __restrict__ K, const float* __restrict__ w_layers,
    float* __restrict__ out_lut, unsigned int* __restrict__ amax)
{
    int e = blockIdx.x * 256 + threadIdx.x;
    float v = 0.f;
    bool valid = e < LUT_ELEMS;
    if (valid) {
        int c = e / DIM3;
        int rem = e - c * DIM3;
        int i = rem / (DIM * DIM);
        int j = (rem / DIM) % DIM;
        int k = rem % DIM;
        int a, col;
        if (c == 0)      { a = k; col = i * DIM + j; }
        else if (c == 1) { a = j; col = i * DIM + k; }
        else             { a = i; col = j * DIM + k; }
        const float* Kr = K + (c * DIM + a) * NFEAT;
#pragma unroll
        for (int w = 0; w < NFEAT; ++w) v = fmaf(Kr[w], w_layers[w * 1089 + col], v);
        out_lut[e] = v;
    }
    float m = valid ? fabsf(v) : 0.f;
#pragma unroll
    for (int off = 32; off >= 1; off >>= 1) m = fmaxf(m, __shfl_down(m, off, 64));
    __shared__ float sm[4];
    int lane = threadIdx.x & 63, wave = threadIdx.x >> 6;
    if (lane == 0) sm[wave] = m;
    __syncthreads();
    if (threadIdx.x == 0) {
        float bm = fmaxf(fmaxf(sm[0], sm[1]), fmaxf(sm[2], sm[3]));
        atomicMax(amax, __float_as_uint(bm));
    }
}

// ---------------- Stage 3: trilinear apply, quantize-in-fill, pipelined -----
__device__ __forceinline__ float sb(unsigned int w, int b) {
    return (float)((int)(w << (24 - 8 * b)) >> 24);   // sign-extended byte b
}

__global__ __launch_bounds__(1024) void apply_lut(
    const float* __restrict__ img, const float* __restrict__ lut,
    const unsigned int* __restrict__ amax, float* __restrict__ out)
{
    extern __shared__ unsigned int qs[];   // 35937 dwords = 143748 B
    float am = __uint_as_float(*amax);
    float inv = 127.0f / am;
    // fill: quantize f32 LUT (L2-resident) straight into LDS, uchar4-packed
    for (int i = threadIdx.x; i < DIM3; i += 1024) {
        int c0 = min(max((int)rintf(lut[i] * inv), -127), 127);
        int c1 = min(max((int)rintf(lut[DIM3 + i] * inv), -127), 127);
        int c2 = min(max((int)rintf(lut[2 * DIM3 + i] * inv), -127), 127);
        qs[i] = (unsigned)(c0 & 0xff) | ((unsigned)(c1 & 0xff) << 8)
              | ((unsigned)(c2 & 0xff) << 16);
    }
    __syncthreads();

    float scale = am * (1.0f / 127.0f);
    constexpr float INV_BIN = 32.0f / 1.000001f;
    const float4* R4 = (const float4*)img;
    const float4* G4 = (const float4*)(img + IMG_HW);
    const float4* B4 = (const float4*)(img + 2 * IMG_HW);
    float* OR = out;
    float* OG = out + IMG_HW;
    float* OB = out + 2 * IMG_HW;

    const int stride = gridDim.x * 1024;
    int t = blockIdx.x * 1024 + threadIdx.x;
    if (t >= NGROUPS) return;
    float4 rv = R4[t], gv = G4[t], bv = B4[t];

    while (true) {
        int tn = t + stride;
        bool more = tn < NGROUPS;
        float4 rv2, gv2, bv2;
        if (more) { rv2 = R4[tn]; gv2 = G4[tn]; bv2 = B4[tn]; }  // prefetch

        float rr[4] = {rv.x, rv.y, rv.z, rv.w};
        float gg[4] = {gv.x, gv.y, gv.z, gv.w};
        float bb[4] = {bv.x, bv.y, bv.z, bv.w};
        float ro[4], go[4], bo[4];
#pragma unroll
        for (int q = 0; q < 4; ++q) {
            float rf = rr[q] * INV_BIN, gf = gg[q] * INV_BIN, bf = bb[q] * INV_BIN;
            float rfl = floorf(rf), gfl = floorf(gf), bfl = floorf(bf);
            int rid = min(max((int)rfl, 0), DIM - 2);
            int gid = min(max((int)gfl, 0), DIM - 2);
            int bid = min(max((int)bfl, 0), DIM - 2);
            float rd = rf - rfl, gd = gf - gfl, bd = bf - bfl;
            float accR = 0.f, accG = 0.f, accB = 0.f;
            int base = (bid * DIM + gid) * DIM + rid;
#pragma unroll
            for (int db = 0; db < 2; ++db) {
                float wb = db ? bd : 1.0f - bd;
#pragma unroll
                for (int dg = 0; dg < 2; ++dg) {
                    float w2 = wb * (dg ? gd : 1.0f - gd);
                    int idx = base + (db * DIM + dg) * DIM;
                    unsigned int lo = qs[idx], hi = qs[idx + 1];  // ds_read2_b32
                    float w0 = w2 * (1.0f - rd), w1 = w2 * rd;
                    accR = fmaf(w0, sb(lo, 0), fmaf(w1, sb(hi, 0), accR));
                    accG = fmaf(w0, sb(lo, 1), fmaf(w1, sb(hi, 1), accG));
                    accB = fmaf(w0, sb(lo, 2), fmaf(w1, sb(hi, 2), accB));
                }
            }
            ro[q] = fmaf(scale, accR, rr[q]);
            go[q] = fmaf(scale, accG, gg[q]);
            bo[q] = fmaf(scale, accB, bb[q]);
        }
        f32x4 o0 = {ro[0], ro[1], ro[2], ro[3]};
        f32x4 o1 = {go[0], go[1], go[2], go[3]};
        f32x4 o2 = {bo[0], bo[1], bo[2], bo[3]};
        __builtin_nontemporal_store(o0, (f32x4*)(OR + 4 * (size_t)t));
        __builtin_nontemporal_store(o1, (f32x4*)(OG + 4 * (size_t)t));
        __builtin_nontemporal_store(o2, (f32x4*)(OB + 4 * (size_t)t));

        if (!more) break;
        t = tn; rv = rv2; gv = gv2; bv = bv2;
    }
}

extern "C" void kernel_launch(void* const* d_in, const int* in_sizes, int n_in,
                              void* d_out, int out_size, void* d_ws, size_t ws_size,
                              hipStream_t stream) {
    const int*   img_msb     = (const int*)d_in[0];
    const int*   img_lsb     = (const int*)d_in[1];
    const float* img_org     = (const float*)d_in[2];
    const float* feature_msb = (const float*)d_in[3];
    const float* feature_lsb = (const float*)d_in[4];
    const float* lut_cat     = (const float*)d_in[5];
    const float* s_layers    = (const float*)d_in[6];
    const float* w_layers    = (const float*)d_in[7];
    const float* luts        = (const float*)d_in[8];
    float* out = (float*)d_out;

    unsigned int* wsu     = (unsigned int*)d_ws;
    unsigned int* amax    = wsu;          // [0]
    unsigned int* counter = wsu + 1;      // [1]
    float*        partial = (float*)d_ws + 16;    // 2560 floats
    float*        K       = (float*)d_ws + 4096;  // 990 floats

    static const size_t LDS_BYTES = DIM3 * sizeof(unsigned int);  // 143748
    hipFuncSetAttribute((const void*)apply_lut,
                        hipFuncAttributeMaxDynamicSharedMemorySize, (int)LDS_BYTES);

    hipMemsetAsync(wsu, 0, 8, stream);   // amax + counter
    feat_and_K<<<256, 256, 0, stream>>>(img_msb, img_lsb, feature_msb, feature_lsb,
                                        lut_cat, s_layers, luts, partial, counter, K);
    compute_lut<<<(LUT_ELEMS + 255) / 256, 256, 0, stream>>>(K, w_layers,
                                                             out + IMG_ELEMS, amax);
    apply_lut<<<256, 1024, LDS_BYTES, stream>>>(img_org, out + IMG_ELEMS, amax, out);
}

// Round 4
// 229.457 us; speedup vs baseline: 1.0312x; 1.0312x over previous
//
#include <hip/hip_runtime.h>

#define HW_S   65536      // 256*256 small image pixels
#define NFEAT  10
#define DIM    33
#define DIM3   35937      // 33^3
#define LUT_ELEMS (3*DIM3)
#define IMG_HW 8294400    // 2160*3840
#define IMG_ELEMS (3*IMG_HW)
#define NGROUPS (IMG_HW/4)

typedef float f32x4 __attribute__((ext_vector_type(4)));

// ws layout (32-bit slots): [0]=amax bits, [1]=counter, [16..2576)=partials,
// [4096..5086)=K, [8448..44385)=quantized LUT dwords

// ---------------- Stage 1: gather+pool, last block computes K ---------------
__global__ __launch_bounds__(256) void feat_and_K(
    const int* __restrict__ msb, const int* __restrict__ lsb,
    const float* __restrict__ fm, const float* __restrict__ fl,
    const float* __restrict__ lut_cat, const float* __restrict__ s_layers,
    const float* __restrict__ luts,
    float* __restrict__ partial, unsigned int* __restrict__ counter,
    float* __restrict__ Kout)
{
    int tid = threadIdx.x;
    int p = blockIdx.x * 256 + tid;
    int im = msb[p] * 4096 + msb[HW_S + p] * 256 + msb[2 * HW_S + p] * 16;
    int il = lsb[p] * 4096 + lsb[HW_S + p] * 256 + lsb[2 * HW_S + p] * 16;
    const float2* rm = (const float2*)(fm + im * NFEAT);  // 40B rows: 8B aligned
    const float2* rl = (const float2*)(fl + il * NFEAT);
    float acc[NFEAT];
#pragma unroll
    for (int h = 0; h < 5; ++h) {
        float2 a = rm[h], b = rl[h];
        acc[2 * h]     = a.x + b.x;
        acc[2 * h + 1] = a.y + b.y;
    }
#pragma unroll
    for (int f = 0; f < NFEAT; ++f) {
        float v = acc[f];
#pragma unroll
        for (int off = 32; off >= 1; off >>= 1) v += __shfl_down(v, off, 64);
        acc[f] = v;
    }
    __shared__ float s4[4][NFEAT];
    int lane = tid & 63, wave = tid >> 6;
    if (lane == 0) {
#pragma unroll
        for (int f = 0; f < NFEAT; ++f) s4[wave][f] = acc[f];
    }
    __syncthreads();
    if (tid < NFEAT)
        partial[blockIdx.x * NFEAT + tid] =
            s4[0][tid] + s4[1][tid] + s4[2][tid] + s4[3][tid];

    // ---- last-block finalization (decoupled, device-scope fenced) ----
    __shared__ int lastflag;
    __syncthreads();   // drains the partial[] stores
    if (tid == 0) {
        __threadfence();
        lastflag = (atomicAdd(counter, 1u) == 255u) ? 1 : 0;
    }
    __syncthreads();
    if (!lastflag) return;
    __threadfence();   // acquire before reading other blocks' partials

    __shared__ float chunk_s[80];
    __shared__ float pooled_s[NFEAT], w_s[NFEAT], R_s[150];
    if (tid < 80) {   // fixed-order tree: 8 chunks x 32 blocks, per feature
        int f = tid % 10, ch = tid / 10;
        float s = 0.f;
        for (int b = ch * 32; b < ch * 32 + 32; ++b) s += partial[b * NFEAT + f];
        chunk_s[tid] = s;
    }
    __syncthreads();
    if (tid < NFEAT) {
        float v = 0.f;
#pragma unroll
        for (int ch = 0; ch < 8; ++ch) v += chunk_s[ch * 10 + tid];
        v *= (1.0f / 65536.0f);
        v = rintf(v * 2.0f) * 0.5f;
        v = fminf(fmaxf(v, -16.0f), 15.5f);
        pooled_s[tid] = v;
    }
    __syncthreads();
    if (tid < NFEAT) {
        float wsum = 0.f;
        for (int i = 0; i < 5; ++i) {
            int m0 = (int)(pooled_s[2 * i] * 2.0f) + 32;
            int m1 = (int)(pooled_s[2 * i + 1] * 2.0f) + 32;
            wsum += (lut_cat[(i * 4096 + m0 * 64 + m1) * NFEAT + tid] - 32.0f) * 0.25f;
        }
        w_s[tid] = wsum;
    }
    __syncthreads();
    if (tid < 150) {  // R[s][c][w] = sum_n weights[n] * luts[s*30+n*3+c, w]
        int w = tid % 10, sc = tid / 10, c = sc % 3, s = sc / 3;
        float r = 0.f;
        for (int n = 0; n < NFEAT; ++n)
            r += w_s[n] * luts[(s * 30 + n * 3 + c) * NFEAT + w];
        R_s[tid] = r;
    }
    __syncthreads();
    for (int t = tid; t < 3 * DIM * NFEAT; t += 256) {  // K[c][a][w]
        int w = t % 10, a = (t / 10) % DIM, c = t / (10 * DIM);
        float k = 0.f;
#pragma unroll
        for (int s = 0; s < 5; ++s)
            k += s_layers[a * 5 + s] * R_s[(s * 3 + c) * 10 + w];
        Kout[t] = k;
    }
}

// ---------------- Stage 2: materialize d3lut (f32) + global absmax ----------
__global__ __launch_bounds__(256) void compute_lut(
    const float* __restrict__ K, const float* __restrict__ w_layers,
    float* __restrict__ out_lut, unsigned int* __restrict__ amax)
{
    int e = blockIdx.x * 256 + threadIdx.x;
    float v = 0.f;
    bool valid = e < LUT_ELEMS;
    if (valid) {
        int c = e / DIM3;
        int rem = e - c * DIM3;
        int i = rem / (DIM * DIM);
        int j = (rem / DIM) % DIM;
        int k = rem % DIM;
        int a, col;
        if (c == 0)      { a = k; col = i * DIM + j; }
        else if (c == 1) { a = j; col = i * DIM + k; }
        else             { a = i; col = j * DIM + k; }
        const float* Kr = K + (c * DIM + a) * NFEAT;
#pragma unroll
        for (int w = 0; w < NFEAT; ++w) v = fmaf(Kr[w], w_layers[w * 1089 + col], v);
        out_lut[e] = v;
    }
    float m = valid ? fabsf(v) : 0.f;
#pragma unroll
    for (int off = 32; off >= 1; off >>= 1) m = fmaxf(m, __shfl_down(m, off, 64));
    __shared__ float sm[4];
    int lane = threadIdx.x & 63, wave = threadIdx.x >> 6;
    if (lane == 0) sm[wave] = m;
    __syncthreads();
    if (threadIdx.x == 0) {
        float bm = fmaxf(fmaxf(sm[0], sm[1]), fmaxf(sm[2], sm[3]));
        atomicMax(amax, __float_as_uint(bm));
    }
}

// ---------------- Stage 3: pack LUT to interleaved int8 (uchar4/entry) ------
__global__ __launch_bounds__(256) void quantize_lut(
    const float* __restrict__ lut, const unsigned int* __restrict__ amax,
    unsigned int* __restrict__ q)
{
    int i = blockIdx.x * 256 + threadIdx.x;
    if (i >= DIM3) return;
    float inv = 127.0f / __uint_as_float(*amax);
    int c0 = min(max((int)rintf(lut[i] * inv), -127), 127);
    int c1 = min(max((int)rintf(lut[DIM3 + i] * inv), -127), 127);
    int c2 = min(max((int)rintf(lut[2 * DIM3 + i] * inv), -127), 127);
    q[i] = (unsigned)(c0 & 0xff) | ((unsigned)(c1 & 0xff) << 8)
         | ((unsigned)(c2 & 0xff) << 16);
}

// ---------------- Stage 4: trilinear apply, two-phase issue/consume ---------
__device__ __forceinline__ float sb(unsigned int w, int b) {
    return (float)((int)(w << (24 - 8 * b)) >> 24);   // sign-extended byte b
}

__global__ __launch_bounds__(1024) void apply_lut(
    const float* __restrict__ img, const unsigned int* __restrict__ qtab,
    const unsigned int* __restrict__ amax, float* __restrict__ out)
{
    extern __shared__ unsigned int qs[];   // 35937 dwords = 143748 B
    for (int i = threadIdx.x; i < 8984; i += 1024)
        ((uint4*)qs)[i] = ((const uint4*)qtab)[i];
    if (threadIdx.x == 0) qs[35936] = qtab[35936];
    __syncthreads();

    float scale = __uint_as_float(*amax) * (1.0f / 127.0f);
    constexpr float INV_BIN = 32.0f / 1.000001f;
    const float4* R4 = (const float4*)img;
    const float4* G4 = (const float4*)(img + IMG_HW);
    const float4* B4 = (const float4*)(img + 2 * IMG_HW);

    for (int t = blockIdx.x * 1024 + threadIdx.x; t < NGROUPS;
         t += gridDim.x * 1024) {
        float4 rv = R4[t], gv = G4[t], bv = B4[t];
        float rr[4] = {rv.x, rv.y, rv.z, rv.w};
        float gg[4] = {gv.x, gv.y, gv.z, gv.w};
        float bb[4] = {bv.x, bv.y, bv.z, bv.w};

        // phase 1: all indices + weights; issue ALL 16 LDS pair-reads
        unsigned int lo[16], hi[16];
        float w2[16], rdv[4];
#pragma unroll
        for (int q = 0; q < 4; ++q) {
            float rf = rr[q] * INV_BIN, gf = gg[q] * INV_BIN, bf = bb[q] * INV_BIN;
            float rfl = floorf(rf), gfl = floorf(gf), bfl = floorf(bf);
            int rid = min(max((int)rfl, 0), DIM - 2);
            int gid = min(max((int)gfl, 0), DIM - 2);
            int bid = min(max((int)bfl, 0), DIM - 2);
            float rd = rf - rfl, gd = gf - gfl, bd = bf - bfl;
            rdv[q] = rd;
            int base = (bid * DIM + gid) * DIM + rid;
#pragma unroll
            for (int db = 0; db < 2; ++db) {
                float wb = db ? bd : 1.0f - bd;
#pragma unroll
                for (int dg = 0; dg < 2; ++dg) {
                    int j = q * 4 + db * 2 + dg;
                    w2[j] = wb * (dg ? gd : 1.0f - gd);
                    int idx = base + (db * DIM + dg) * DIM;
                    lo[j] = qs[idx];          // ds_read2_b32, 16 outstanding
                    hi[j] = qs[idx + 1];
                }
            }
        }
        // phase 2: consume (lgkmcnt partial waits overlap VALU with LDS)
        float ro[4], go[4], bo[4];
#pragma unroll
        for (int q = 0; q < 4; ++q) {
            float rd = rdv[q], accR = 0.f, accG = 0.f, accB = 0.f;
#pragma unroll
            for (int jj = 0; jj < 4; ++jj) {
                int j = q * 4 + jj;
                float w0 = w2[j] * (1.0f - rd), w1 = w2[j] * rd;
                accR = fmaf(w0, sb(lo[j], 0), fmaf(w1, sb(hi[j], 0), accR));
                accG = fmaf(w0, sb(lo[j], 1), fmaf(w1, sb(hi[j], 1), accG));
                accB = fmaf(w0, sb(lo[j], 2), fmaf(w1, sb(hi[j], 2), accB));
            }
            ro[q] = fmaf(scale, accR, rr[q]);
            go[q] = fmaf(scale, accG, gg[q]);
            bo[q] = fmaf(scale, accB, bb[q]);
        }
        ((float4*)out)[t]                = make_float4(ro[0], ro[1], ro[2], ro[3]);
        ((float4*)(out + IMG_HW))[t]     = make_float4(go[0], go[1], go[2], go[3]);
        ((float4*)(out + 2 * IMG_HW))[t] = make_float4(bo[0], bo[1], bo[2], bo[3]);
    }
}

extern "C" void kernel_launch(void* const* d_in, const int* in_sizes, int n_in,
                              void* d_out, int out_size, void* d_ws, size_t ws_size,
                              hipStream_t stream) {
    const int*   img_msb     = (const int*)d_in[0];
    const int*   img_lsb     = (const int*)d_in[1];
    const float* img_org     = (const float*)d_in[2];
    const float* feature_msb = (const float*)d_in[3];
    const float* feature_lsb = (const float*)d_in[4];
    const float* lut_cat     = (const float*)d_in[5];
    const float* s_layers    = (const float*)d_in[6];
    const float* w_layers    = (const float*)d_in[7];
    const float* luts        = (const float*)d_in[8];
    float* out = (float*)d_out;

    unsigned int* wsu     = (unsigned int*)d_ws;
    unsigned int* amax    = wsu;                   // [0]
    unsigned int* counter = wsu + 1;               // [1]
    float*        partial = (float*)d_ws + 16;     // 2560 floats
    float*        K       = (float*)d_ws + 4096;   // 990 floats
    unsigned int* q       = wsu + 8448;            // 35937 dwords, 16B aligned

    static const size_t LDS_BYTES = DIM3 * sizeof(unsigned int);  // 143748
    hipFuncSetAttribute((const void*)apply_lut,
                        hipFuncAttributeMaxDynamicSharedMemorySize, (int)LDS_BYTES);

    hipMemsetAsync(wsu, 0, 8, stream);   // amax + counter
    feat_and_K<<<256, 256, 0, stream>>>(img_msb, img_lsb, feature_msb, feature_lsb,
                                        lut_cat, s_layers, luts, partial, counter, K);
    compute_lut<<<(LUT_ELEMS + 255) / 256, 256, 0, stream>>>(K, w_layers,
                                                             out + IMG_ELEMS, amax);
    quantize_lut<<<(DIM3 + 255) / 256, 256, 0, stream>>>(out + IMG_ELEMS, amax, q);
    apply_lut<<<512, 1024, LDS_BYTES, stream>>>(img_org, q, amax, out);
}